// Round 7
// baseline (444.339 us; speedup 1.0000x reference)
//
#include <hip/hip_runtime.h>
#include <hip/hip_bf16.h>

typedef __attribute__((ext_vector_type(8))) short short8;
typedef __attribute__((ext_vector_type(16))) float f32x16;

#define CC 0.01f
#define SCRT 0.1f  // sqrt(c)

static __device__ __forceinline__ unsigned short f2bf(float f) {
  union { float f; unsigned int u; } cv; cv.f = f;
  unsigned int u = cv.u;
  unsigned int r = (u + 0x7fffu + ((u >> 16) & 1u)) >> 16;  // RNE
  return (unsigned short)r;
}
static __device__ __forceinline__ float bf2f(unsigned short u) {
  union { unsigned int u; float f; } cv; cv.u = ((unsigned int)u) << 16;
  return cv.f;
}

#define GLOAD16(g, l) __builtin_amdgcn_global_load_lds( \
    (const __attribute__((address_space(1))) void*)(g), \
    (__attribute__((address_space(3))) void*)(l), 16, 0, 0)

// ---------------------------------------------------------------------------
__global__ void k_prep_sto(const float* __restrict__ ent,
                           const int* __restrict__ trip,
                           unsigned short* __restrict__ sto) {
  int i = blockIdx.x;
  int t = threadIdx.x;
  size_t si = (size_t)trip[i * 3 + 0];
  size_t oi = (size_t)trip[i * 3 + 2];
  float4 vs = ((const float4*)(ent + si * 1024))[t];
  float4 vo = ((const float4*)(ent + oi * 1024))[t];
  float ss = vs.x * vs.x + vs.y * vs.y + vs.z * vs.z + vs.w * vs.w;
  float so = vo.x * vo.x + vo.y * vo.y + vo.z * vo.z + vo.w * vo.w;
#pragma unroll
  for (int off = 32; off > 0; off >>= 1) {
    ss += __shfl_down(ss, off, 64);
    so += __shfl_down(so, off, 64);
  }
  __shared__ float red[8];
  if ((t & 63) == 0) { red[t >> 6] = ss; red[4 + (t >> 6)] = so; }
  __syncthreads();
  float tot_s = red[0] + red[1] + red[2] + red[3];
  float tot_o = red[4] + red[5] + red[6] + red[7];

  float ns = fmaxf(sqrtf(tot_s), 1e-10f);
  float scn_s = SCRT * ns;
  float fs = atanhf(fminf(scn_s, 1.0f - 1e-7f)) / scn_s;

  float no = fmaxf(sqrtf(tot_o), 1e-10f);
  float scn_o = SCRT * no;
  float fo = atanhf(fminf(scn_o, 1.0f - 1e-7f)) / scn_o;

  ushort4 os, oo;
  os.x = f2bf(vs.x * fs); os.y = f2bf(vs.y * fs);
  os.z = f2bf(vs.z * fs); os.w = f2bf(vs.w * fs);
  oo.x = f2bf(vo.x * fo); oo.y = f2bf(vo.y * fo);
  oo.z = f2bf(vo.z * fo); oo.w = f2bf(vo.w * fo);
  ((ushort4*)(sto + (size_t)i * 2048))[t] = os;
  ((ushort4*)(sto + (size_t)i * 2048 + 1024))[t] = oo;
}

// ---------------------------------------------------------------------------
__global__ void k_wt(const float* __restrict__ Ws, const float* __restrict__ Wo,
                     unsigned short* __restrict__ wtb) {
  int idx = blockIdx.x * 256 + threadIdx.x;   // 1024*2048 total
  int n = idx >> 11;
  int k = idx & 2047;
  float v = (k < 1024) ? Ws[k * 1024 + n] : Wo[(k - 1024) * 1024 + n];
  wtb[idx] = f2bf(v);
}

// ---------------------------------------------------------------------------
__global__ void k_rel(const float* __restrict__ rel,
                      unsigned short* __restrict__ relb,
                      float* __restrict__ yy, float* __restrict__ fj) {
  int j = blockIdx.x;
  int t = threadIdx.x;
  float4 v = ((const float4*)(rel + (size_t)j * 1024))[t];
  float ss = v.x * v.x + v.y * v.y + v.z * v.z + v.w * v.w;
#pragma unroll
  for (int off = 32; off > 0; off >>= 1) ss += __shfl_down(ss, off, 64);
  __shared__ float red[4];
  if ((t & 63) == 0) red[t >> 6] = ss;
  __syncthreads();
  ushort4 o;
  o.x = f2bf(v.x); o.y = f2bf(v.y); o.z = f2bf(v.z); o.w = f2bf(v.w);
  ((ushort4*)(relb + (size_t)j * 1024))[t] = o;
  if (t == 0) {
    float tot = red[0] + red[1] + red[2] + red[3];
    float n = fmaxf(sqrtf(tot), 1e-10f);
    float scn = SCRT * n;
    float f = tanhf(scn) / scn;
    yy[j] = f * f * tot;
    fj[j] = f;
  }
}

// ---------------------------------------------------------------------------
__global__ void k_qstat(const unsigned short* __restrict__ qt,
                        float* __restrict__ xx, float* __restrict__ fi) {
  int i = blockIdx.x;
  int t = threadIdx.x;
  ushort4 v = ((const ushort4*)(qt + (size_t)i * 1024))[t];
  float a = bf2f(v.x), b = bf2f(v.y), c = bf2f(v.z), d = bf2f(v.w);
  float ss = a * a + b * b + c * c + d * d;
#pragma unroll
  for (int off = 32; off > 0; off >>= 1) ss += __shfl_down(ss, off, 64);
  __shared__ float red[4];
  if ((t & 63) == 0) red[t >> 6] = ss;
  __syncthreads();
  if (t == 0) {
    float tot = red[0] + red[1] + red[2] + red[3];
    float n = fmaxf(sqrtf(tot), 1e-10f);
    float scn = SCRT * n;
    float f = tanhf(scn) / scn;
    xx[i] = f * f * tot;
    fi[i] = f;
  }
}

// ---------------------------------------------------------------------------
// 8-phase 256x256 GEMM with 32x32x16 bf16 MFMA. BK=64, 8 waves (2M x 4N),
// 2 LDS dbufs. Same phase/stage/barrier/vmcnt skeleton as R6 (race-free);
// only the MFMA shape, fragment reads, and epilogue C-mapping change.
#define PH_OPEN() do { __builtin_amdgcn_sched_barrier(0); \
    __builtin_amdgcn_s_barrier(); \
    asm volatile("s_waitcnt lgkmcnt(0)" ::: "memory"); \
    __builtin_amdgcn_sched_barrier(0); \
    __builtin_amdgcn_s_setprio(1); } while (0)
#define PH_CLOSE() do { __builtin_amdgcn_s_setprio(0); \
    __builtin_amdgcn_sched_barrier(0); \
    __builtin_amdgcn_s_barrier(); } while (0)
#define VMW(n) asm volatile("s_waitcnt vmcnt(" #n ")" ::: "memory")

template<int K, bool G2>
__global__ __launch_bounds__(512, 2) void k_gemm8p(
    const unsigned short* __restrict__ A,
    const unsigned short* __restrict__ BT,
    unsigned short* __restrict__ Cq,
    const float* __restrict__ xx, const float* __restrict__ fi,
    const float* __restrict__ yy, const float* __restrict__ fj,
    const float* __restrict__ bias, float* __restrict__ out,
    int nxb) {
  constexpr int NT = K / 64;
  constexpr int NI = NT / 2;
  __shared__ __align__(16) unsigned short AS[2 * 16384];   // 64 KB
  __shared__ __align__(16) unsigned short BS[2 * 16384];   // 64 KB
  char* asc = (char*)AS;
  char* bsc = (char*)BS;

  int nwg = gridDim.x, bid = blockIdx.x;
  int wg = (bid & 7) * (nwg >> 3) + (bid >> 3);
  int bx = wg % nxb, by = wg / nxb;
  size_t gm0 = (size_t)by * 256;
  int gn0 = bx * 256;

  int t = threadIdx.x, lane = t & 63, w = t >> 6;
  int wm = w >> 2;      // 0..1 -> 128-row half of C
  int wn = w & 3;       // 0..3 -> 64-col block of C
  int lr = lane & 31;   // row within 32x32 tile
  int hi = lane >> 5;   // k-subgroup
  int wb = w << 10;     // wave-uniform stage dest offset

  // stage sources: thread t covers row (t>>2), chunk (t&3) of a 128-row group
  int srow = t >> 2;
  int csw = (t & 3) ^ ((t >> 3) & 3);    // pre-swizzled source chunk
  const unsigned short* paR0 = A + (gm0 + srow) * (size_t)K + csw * 8;
  const unsigned short* paR1 = paR0 + (size_t)128 * K;
  int brow0 = gn0 + srow, brow1 = gn0 + 128 + srow;
  if (G2) { brow0 = min(brow0, 1999); brow1 = min(brow1, 1999); }
  const unsigned short* pbR0 = BT + (size_t)brow0 * K + csw * 8;
  const unsigned short* pbR1 = BT + (size_t)brow1 * K + csw * 8;

  // fragment read bases: lane reads row lr (32-row granularity), 16B chunk
  // chunk(k16) = (2*k16 + hi) ^ ((lr>>1)&3); k16=1 base = k16=0 base XOR 32
  unsigned xr = (unsigned)((lr >> 1) & 3);
  unsigned rba = (unsigned)((wm * 128 + lr) * 64) + ((hi ^ xr) << 4);
  unsigned rbb = (unsigned)((wn * 64 + lr) * 64) + ((hi ^ xr) << 4);
  const char* ak0 = asc + rba;
  const char* ak1 = asc + (rba ^ 32u);
  const char* bk0 = bsc + rbb;
  const char* bk1 = bsc + (rbb ^ 32u);

#define STAGE_A(kt, DB) do { \
    GLOAD16(paR0 + (size_t)(kt) * 64,      asc + (DB) + wb); \
    GLOAD16(paR1 + (size_t)(kt) * 64,      asc + (DB) + 8192 + wb); \
    GLOAD16(paR0 + (size_t)(kt) * 64 + 32, asc + (DB) + 16384 + wb); \
    GLOAD16(paR1 + (size_t)(kt) * 64 + 32, asc + (DB) + 16384 + 8192 + wb); \
  } while (0)
#define STAGE_B(kt, DB) do { \
    GLOAD16(pbR0 + (size_t)(kt) * 64,      bsc + (DB) + wb); \
    GLOAD16(pbR1 + (size_t)(kt) * 64,      bsc + (DB) + 8192 + wb); \
    GLOAD16(pbR0 + (size_t)(kt) * 64 + 32, bsc + (DB) + 16384 + wb); \
    GLOAD16(pbR1 + (size_t)(kt) * 64 + 32, bsc + (DB) + 16384 + 8192 + wb); \
  } while (0)
  // s = kstep (0..3): khalf = s>>1 (16384), k16 = s&1 (base sel), mb*2048 rows
#define RDA(BUF, s, mb) (*(const short8*)( ((s) & 1 ? ak1 : ak0) + (BUF) + ((s) >> 1) * 16384 + (mb) * 2048 ))
#define RDB(BUF, s, nb) (*(const short8*)( ((s) & 1 ? bk1 : bk0) + (BUF) + ((s) >> 1) * 16384 + (nb) * 2048 ))
  // Quadrant (mp, n): m-tiles {2mp,2mp+1} x col-tile n over full K=64.
  // afr[m2][s] held in regs; dep-chain distance 2 (m2 inner).
#define QUAD32(mp, n, bb) do { \
    _Pragma("unroll") for (int s_ = 0; s_ < 4; ++s_) \
    _Pragma("unroll") for (int m2_ = 0; m2_ < 2; ++m2_) \
      acc[2 * (mp) + m2_][n] = __builtin_amdgcn_mfma_f32_32x32x16_bf16( \
          afr[m2_][s_], bb[s_], acc[2 * (mp) + m2_][n], 0, 0, 0); \
  } while (0)

  f32x16 acc[4][2] = {};
  short8 afr[2][4], b0v[4], b1v[4];

  // ---- prologue: stage tiles 0 (buf0) and 1 (buf1); retire tile 0.
  STAGE_B(0, 0); STAGE_A(0, 0);
  STAGE_B(1, 32768); STAGE_A(1, 32768);
  VMW(8);                                  // tile 0 (first 8 loads) landed
  __builtin_amdgcn_s_barrier();
  __builtin_amdgcn_sched_barrier(0);

  for (int it = 0; it < NI; ++it) {
    bool st = (it < NI - 1);
    int kn0 = 2 * it + 2;                  // next-iter tile0 -> buf0
    int kn1 = 2 * it + 3;                  // next-iter tile1 -> buf1

    // ================= tile t0 (buf 0) =================
    // P1: read A m0,m1 (8) + B n0 (4); MFMA Q(0,0)
#pragma unroll
    for (int m2 = 0; m2 < 2; ++m2)
#pragma unroll
      for (int s = 0; s < 4; ++s) afr[m2][s] = RDA(0, s, m2);
#pragma unroll
    for (int s = 0; s < 4; ++s) b0v[s] = RDB(0, s, 0);
    PH_OPEN(); QUAD32(0, 0, b0v); PH_CLOSE();
    // P2: read B n1 (4); MFMA Q(0,1)
#pragma unroll
    for (int s = 0; s < 4; ++s) b1v[s] = RDB(0, s, 1);
    PH_OPEN(); QUAD32(0, 1, b1v); PH_CLOSE();
    // P3: read A m2,m3 (8); stage B(kn0) into buf0-B (free since P2); Q(1,0)
#pragma unroll
    for (int m2 = 0; m2 < 2; ++m2)
#pragma unroll
      for (int s = 0; s < 4; ++s) afr[m2][s] = RDA(0, s, m2 + 2);
    if (st) STAGE_B(kn0, 0);
    PH_OPEN(); QUAD32(1, 0, b0v); PH_CLOSE();
    // P4: stage A(kn0) into buf0-A (free since P3); gate tile t1; Q(1,1)
    if (st) {
      STAGE_A(kn0, 0);
      VMW(8);                              // retires tile t1's 8 loads
    } else {
      VMW(0);
    }
    PH_OPEN(); QUAD32(1, 1, b1v); PH_CLOSE();

    // ================= tile t1 (buf 32768) =================
    // P5
#pragma unroll
    for (int m2 = 0; m2 < 2; ++m2)
#pragma unroll
      for (int s = 0; s < 4; ++s) afr[m2][s] = RDA(32768, s, m2);
#pragma unroll
    for (int s = 0; s < 4; ++s) b0v[s] = RDB(32768, s, 0);
    PH_OPEN(); QUAD32(0, 0, b0v); PH_CLOSE();
    // P6
#pragma unroll
    for (int s = 0; s < 4; ++s) b1v[s] = RDB(32768, s, 1);
    PH_OPEN(); QUAD32(0, 1, b1v); PH_CLOSE();
    // P7
#pragma unroll
    for (int m2 = 0; m2 < 2; ++m2)
#pragma unroll
      for (int s = 0; s < 4; ++s) afr[m2][s] = RDA(32768, s, m2 + 2);
    if (st) STAGE_B(kn1, 32768);
    PH_OPEN(); QUAD32(1, 0, b0v); PH_CLOSE();
    // P8
    if (st) {
      STAGE_A(kn1, 32768);
      VMW(8);                              // retires next-iter tile0's 8 loads
    }
    PH_OPEN(); QUAD32(1, 1, b1v); PH_CLOSE();
  }

  // ---- epilogue (32x32 C/D: col = lane&31, row = (reg&3)+8*(reg>>2)+4*hi)
  if (!G2) {
#pragma unroll
    for (int mb = 0; mb < 4; ++mb)
#pragma unroll
      for (int nb = 0; nb < 2; ++nb) {
        int col = gn0 + wn * 64 + nb * 32 + lr;
        size_t rowb = gm0 + wm * 128 + mb * 32 + 4 * hi;
#pragma unroll
        for (int q = 0; q < 4; ++q)
#pragma unroll
          for (int j = 0; j < 4; ++j)
            Cq[(rowb + q * 8 + j) * 1024 + col] = f2bf(acc[mb][nb][q * 4 + j]);
      }
  } else {
#pragma unroll
    for (int mb = 0; mb < 4; ++mb)
#pragma unroll
      for (int nb = 0; nb < 2; ++nb) {
        int col = gn0 + wn * 64 + nb * 32 + lr;
        if (col < 2000) {
          float yj = yy[col], fjc = fj[col], bj = bias[col];
          size_t rowb = gm0 + wm * 128 + mb * 32 + 4 * hi;
#pragma unroll
          for (int q = 0; q < 4; ++q)
#pragma unroll
            for (int j = 0; j < 4; ++j) {
              size_t row = rowb + q * 8 + j;
              float G = acc[mb][nb][q * 4 + j];
              float xi = xx[row], fic = fi[row];
              float xyv = -(fic * fjc) * G;
              float Aa = 1.0f + 2.0f * CC * xyv + CC * yj;
              float Bb = 1.0f - CC * xi;
              float num = Aa * Aa * xi + 2.0f * Aa * Bb * xyv + Bb * Bb * yj;
              float den = 1.0f + 2.0f * CC * xyv + CC * CC * xi * yj;
              out[row * 2000 + col] = -(num / (den * den)) + bj;
            }
        }
      }
  }
#undef STAGE_A
#undef STAGE_B
#undef RDA
#undef RDB
#undef QUAD32
}

// ---------------------------------------------------------------------------
extern "C" void kernel_launch(void* const* d_in, const int* in_sizes, int n_in,
                              void* d_out, int out_size, void* d_ws, size_t ws_size,
                              hipStream_t stream) {
  const float* ent = (const float*)d_in[0];
  const float* rel = (const float*)d_in[1];
  const int* trip = (const int*)d_in[2];
  const float* Ws = (const float*)d_in[3];
  const float* Wo = (const float*)d_in[4];
  const float* bias = (const float*)d_in[5];
  float* out = (float*)d_out;

  char* ws = (char*)d_ws;
  unsigned short* sto = (unsigned short*)(ws);                    // 32768*2048*2 = 134217728
  unsigned short* wt  = (unsigned short*)(ws + 134217728);        // 1024*2048*2  =   4194304
  unsigned short* qt  = (unsigned short*)(ws + 138412032);        // 32768*1024*2 =  67108864
  unsigned short* relb= (unsigned short*)(ws + 205520896);        // 2000*1024*2  =   4096000
  float* xx = (float*)(ws + 209616896);                           // 131072
  float* fi = (float*)(ws + 209747968);                           // 131072
  float* yy = (float*)(ws + 209879040);                           // 8192
  float* fj = (float*)(ws + 209887232);                           // 8192

  k_prep_sto<<<dim3(32768), dim3(256), 0, stream>>>(ent, trip, sto);
  k_wt<<<dim3((1024 * 2048) / 256), dim3(256), 0, stream>>>(Ws, Wo, wt);
  k_rel<<<dim3(2000), dim3(256), 0, stream>>>(rel, relb, yy, fj);

  // GEMM1: qt[32768][1024] = sto[32768][2048] @ wt^T ; grid 4x128 = 512
  k_gemm8p<2048, false><<<dim3(512), dim3(512), 0, stream>>>(
      sto, wt, qt, xx, fi, yy, fj, bias, out, 4);

  k_qstat<<<dim3(32768), dim3(256), 0, stream>>>(qt, xx, fi);

  // GEMM2 + epilogue: grid 8x128 = 1024
  k_gemm8p<1024, true><<<dim3(1024), dim3(512), 0, stream>>>(
      qt, relb, qt /*unused*/, xx, fi, yy, fj, bias, out, 8);
}